// Round 5
// baseline (339.582 us; speedup 1.0000x reference)
//
#include <hip/hip_runtime.h>
#include <stdint.h>

#define N 4096

// blocked scratch layout: addr = tile*524288 + kt*16384 + c*2048 + r*16
//   tile = row>>7, r = row&127, kt = kbyte>>7, c = (kbyte>>4)&7
#define TILE_BYTES 524288   // 128 rows * 4096 B
#define KT_BYTES   16384    // 8 chunks * 128 rows * 16 B

#define QSCALE 256.0f            // W -> fp8 software scale (per tensor)
#define INV_QQ (1.0f / 65536.0f) // undo QSCALE^2 on S

typedef int v8i __attribute__((ext_vector_type(8)));
typedef float f32x16 __attribute__((ext_vector_type(16)));
typedef unsigned int u32x4 __attribute__((ext_vector_type(4)));

union V8 { v8i v; u32x4 h[2]; };

__device__ __forceinline__ void gload16(const unsigned char* g, unsigned char* l) {
  __builtin_amdgcn_global_load_lds(
      (const __attribute__((address_space(1))) unsigned int*)g,
      (__attribute__((address_space(3))) unsigned int*)l, 16, 0, 0);
}

// pack 4 floats -> 4 fp8 e4m3 bytes (OCP on gfx950)
__device__ __forceinline__ int pack4_fp8(float a, float b, float c, float d) {
  int r = __builtin_amdgcn_cvt_pk_fp8_f32(a, b, 0, false);
  r = __builtin_amdgcn_cvt_pk_fp8_f32(c, d, r, true);
  return r;
}

// ---- K1: W1 fp32 [k][j] -> fp8 W1T blocked  +  tvec[k] += W1[k][:] . center ----
// Store mapping jl=t&63, ch=(t>>6)*16: each wave's 64 uint4 stores are one
// contiguous 1024-B run (was 2048-B-stride scatter); LDS reads 2-way bank
// aliased (free).
__global__ __launch_bounds__(256) void prep_w1(const float* __restrict__ W1,
                                               const float* __restrict__ lb0,
                                               const float* __restrict__ ub0,
                                               unsigned char* __restrict__ W1T,
                                               float* __restrict__ tvec) {
  __shared__ float tile[64 * 65];
  __shared__ float tdot[64];
  const int t = threadIdx.x;
  const int j0 = blockIdx.x * 64, k0 = blockIdx.y * 64;
#pragma unroll
  for (int s = 0; s < 4; ++s) {
    int ck = s * 256 + t;
    int row = ck >> 4;             // k_local 0..63
    int col = (ck & 15) * 4;       // j_local
    float4 v = *(const float4*)(W1 + (size_t)(k0 + row) * N + j0 + col);
    float4 l = *(const float4*)(lb0 + j0 + col);
    float4 u = *(const float4*)(ub0 + j0 + col);
    float part = v.x * 0.5f * (l.x + u.x) + v.y * 0.5f * (l.y + u.y)
               + v.z * 0.5f * (l.z + u.z) + v.w * 0.5f * (l.w + u.w);
    part += __shfl_xor(part, 1, 64);
    part += __shfl_xor(part, 2, 64);
    part += __shfl_xor(part, 4, 64);
    part += __shfl_xor(part, 8, 64);
    if ((t & 15) == 0) tdot[row] = part;   // each row written exactly once
    float* d = &tile[row * 65 + col];
    d[0] = v.x; d[1] = v.y; d[2] = v.z; d[3] = v.w;
  }
  __syncthreads();
  if (t < 64) atomicAdd(&tvec[k0 + t], tdot[t]);
  int jl = t & 63, ch = (t >> 6) * 16;  // coalesced store mapping
  float f[16];
#pragma unroll
  for (int m = 0; m < 16; ++m) f[m] = tile[(ch + m) * 65 + jl] * QSCALE;
  uint4 o;
  o.x = (unsigned)pack4_fp8(f[0], f[1], f[2], f[3]);
  o.y = (unsigned)pack4_fp8(f[4], f[5], f[6], f[7]);
  o.z = (unsigned)pack4_fp8(f[8], f[9], f[10], f[11]);
  o.w = (unsigned)pack4_fp8(f[12], f[13], f[14], f[15]);
  int j = j0 + jl;
  int kb = k0 + ch;                     // k byte index
  *(uint4*)(W1T + (size_t)(j >> 7) * TILE_BYTES + (size_t)(kb >> 7) * KT_BYTES
            + (size_t)((kb >> 4) & 7) * 2048 + (j & 127) * 16) = o;
}

// ---- K2: W2 -> fp8 blocked, coalesced loads along k, shfl-reduced dots ----
__global__ __launch_bounds__(256) void convert_w2(const float* __restrict__ W2,
                                                  const float* __restrict__ b1,
                                                  const float* __restrict__ tvec,
                                                  unsigned char* __restrict__ W2q,
                                                  float* __restrict__ cvec,
                                                  float* __restrict__ Sc) {
  __shared__ int lpack[128][33];          // +1 pad: conflict-free transpose
  const int t = threadIdx.x;
  const int i0 = blockIdx.y * 128;        // row tile
  const int k0 = blockIdx.x * 128;        // k panel
  const int kl = (t & 31) * 4;            // k offset within panel (floats)
  const int rsub = t >> 5;                // 0..7: row sub-index
  float4 bv = *(const float4*)(b1 + k0 + kl);
  float4 tv = *(const float4*)(tvec + k0 + kl);
#pragma unroll
  for (int s = 0; s < 16; ++s) {
    int row = s * 8 + rsub;
    float4 w = *(const float4*)(W2 + (size_t)(i0 + row) * N + k0 + kl);
    float db = w.x * bv.x + w.y * bv.y + w.z * bv.z + w.w * bv.w;
    float dt = w.x * tv.x + w.y * tv.y + w.z * tv.z + w.w * tv.w;
    db += __shfl_xor(db, 1, 64);  dt += __shfl_xor(dt, 1, 64);
    db += __shfl_xor(db, 2, 64);  dt += __shfl_xor(dt, 2, 64);
    db += __shfl_xor(db, 4, 64);  dt += __shfl_xor(dt, 4, 64);
    db += __shfl_xor(db, 8, 64);  dt += __shfl_xor(dt, 8, 64);
    db += __shfl_xor(db, 16, 64); dt += __shfl_xor(dt, 16, 64);
    if ((t & 31) == 0) {
      atomicAdd(&cvec[i0 + row], db);
      atomicAdd(&Sc[i0 + row], dt);
    }
    lpack[row][t & 31] = pack4_fp8(w.x * QSCALE, w.y * QSCALE,
                                   w.z * QSCALE, w.w * QSCALE);
  }
  __syncthreads();
  unsigned char* panel = W2q + (size_t)blockIdx.y * TILE_BYTES
                       + (size_t)blockIdx.x * KT_BYTES;
#pragma unroll
  for (int q = 0; q < 4; ++q) {
    int cid = q * 256 + t;                // 16-B chunk id 0..1023
    int r = cid & 127, c = cid >> 7;
    uint4 o;
    o.x = (unsigned)lpack[r][4 * c + 0];
    o.y = (unsigned)lpack[r][4 * c + 1];
    o.z = (unsigned)lpack[r][4 * c + 2];
    o.w = (unsigned)lpack[r][4 * c + 3];
    *(uint4*)(panel + (size_t)c * 2048 + r * 16) = o;   // consecutive r -> contiguous
  }
}

// ---- K3: R_i = sum_j |(W2q @ W1Tq^T)_ij| * eps_j  via MX fp8 MFMA 32x32x64 ----
// Round-1 version (best measured: 86.1 us). 4 half-group LDS slots, counted
// vmcnt(8) across barriers, compiler-scheduled ds_reads, setprio'd MFMA.
#define NT 32   // K tiles of 128 bytes
__global__ __launch_bounds__(512, 2) void gemm_absrow(const unsigned char* __restrict__ A,  // W2q blocked
                                                      const unsigned char* __restrict__ B,  // W1Tq blocked
                                                      const float* __restrict__ lb0,
                                                      const float* __restrict__ ub0,
                                                      float* __restrict__ R_acc) {
  __shared__ __align__(16) unsigned char sm[4 * 32768];   // 128 KB, 4 k-half groups
  const int t = threadIdx.x;                // 0..511
  const int lane = t & 63, w = t >> 6;      // 8 waves
  const int wr = w >> 2, wc = w & 3;        // 2 x 4 wave grid
  const int l31 = lane & 31, half = lane >> 5;

  // bijective XCD swizzle (256 blocks, 256 % 8 == 0)
  const int bid = blockIdx.y * 16 + blockIdx.x;
  const int swz = (bid & 7) * 32 + (bid >> 3);
  const int bm = swz >> 4, bn = swz & 15;
  const int i0 = bm * 256, j0 = bn * 256;

  const unsigned char* gA0 = A + (size_t)(2 * bm) * TILE_BYTES + t * 16;
  const unsigned char* gA1 = gA0 + TILE_BYTES;
  const unsigned char* gB0 = B + (size_t)(2 * bn) * TILE_BYTES + t * 16;
  const unsigned char* gB1 = gB0 + TILE_BYTES;

  f32x16 acc[4][2] = {};
  const int sc1 = 0x7F7F7F7F;  // E8M0 scale = 1.0 in all 4 bytes

  // stage tile kt, k-half h -> group ((kt&1)<<1)|h : A lo/hi then B lo/hi
  auto stage = [&](int kt, int h) {
    const int g = ((kt & 1) << 1) | h;
    unsigned char* d = sm + g * 32768 + t * 16;
    const size_t off = (size_t)kt * KT_BYTES + (size_t)h * 8192;
    gload16(gA0 + off, d);
    gload16(gA1 + off, d + 8192);
    gload16(gB0 + off, d + 16384);
    gload16(gB1 + off, d + 24576);
  };

  auto compute = [&](int kt, int h) {
    const unsigned char* base = sm + (((kt & 1) << 1) | h) * 32768;
    V8 af[4], bf[2];
    const unsigned char* pa = base + wr * 8192 + (half * 2) * 2048 + l31 * 16;
#pragma unroll
    for (int tm = 0; tm < 4; ++tm) {
      const unsigned char* p = pa + tm * 512;          // 32 rows * 16 B
      af[tm].h[0] = *(const u32x4*)p;
      af[tm].h[1] = *(const u32x4*)(p + 2048);          // next 16-B k-chunk
    }
#pragma unroll
    for (int tn = 0; tn < 2; ++tn) {
      const int j = wc * 64 + tn * 32 + l31;            // col within 256 block
      const unsigned char* p = base + 16384 + (j >> 7) * 8192
                             + (half * 2) * 2048 + (j & 127) * 16;
      bf[tn].h[0] = *(const u32x4*)p;
      bf[tn].h[1] = *(const u32x4*)(p + 2048);
    }
    __builtin_amdgcn_s_setprio(1);
#pragma unroll
    for (int tm = 0; tm < 4; ++tm)
#pragma unroll
      for (int tn = 0; tn < 2; ++tn)
        acc[tm][tn] = __builtin_amdgcn_mfma_scale_f32_32x32x64_f8f6f4(
            af[tm].v, bf[tn].v, acc[tm][tn],
            0 /*cbsz: fp8*/, 0 /*blgp: fp8*/,
            0, sc1, 0, sc1);
    __builtin_amdgcn_s_setprio(0);
  };

  // prologue: groups G0, G1 (tile 0, both halves)
  stage(0, 0);
  stage(0, 1);

  for (int kt = 0; kt < NT - 1; ++kt) {
#pragma unroll
    for (int h = 0; h < 2; ++h) {
      stage(kt + 1, h);                                  // group P+2
      asm volatile("s_waitcnt vmcnt(8)" ::: "memory");   // group P landed (counted)
      __builtin_amdgcn_s_barrier();                      // all waves' P landed
      asm volatile("" ::: "memory");
      compute(kt, h);
    }
  }
  // tail: kt = NT-1, nothing left to stage
  asm volatile("s_waitcnt vmcnt(4)" ::: "memory");
  __builtin_amdgcn_s_barrier();
  asm volatile("" ::: "memory");
  compute(NT - 1, 0);
  asm volatile("s_waitcnt vmcnt(0)" ::: "memory");
  __builtin_amdgcn_s_barrier();
  asm volatile("" ::: "memory");
  compute(NT - 1, 1);

  // epilogue: eps-weighted row L1 norm. C/D 32x32 layout:
  // col = lane&31, row = (r&3) + 8*(r>>2) + 4*(lane>>5)
  float epsv[2];
#pragma unroll
  for (int tn = 0; tn < 2; ++tn) {
    int j = j0 + wc * 64 + tn * 32 + l31;
    epsv[tn] = 0.5f * (ub0[j] - lb0[j]);
  }
#pragma unroll
  for (int tm = 0; tm < 4; ++tm) {
#pragma unroll
    for (int r = 0; r < 16; ++r) {
      float s = fabsf(acc[tm][0][r]) * epsv[0] + fabsf(acc[tm][1][r]) * epsv[1];
#pragma unroll
      for (int off = 1; off < 32; off <<= 1)   // reduce within each 32-lane half
        s += __shfl_xor(s, off, 64);
      if (l31 == 0) {
        int i = i0 + wr * 128 + tm * 32 + (r & 3) + 8 * (r >> 2) + 4 * half;
        atomicAdd(&R_acc[i], s);
      }
    }
  }
}

// ---- K4: sparse DeepPolyReLU patch after bulk hipMemsetAsync zero-fill ----
struct ReluVals { float lslope, uslope, uinter; };

__device__ __forceinline__ ReluVals relu_vals(int i,
                                              const float* __restrict__ cvec,
                                              const float* __restrict__ Sc,
                                              const float* __restrict__ b2,
                                              const float* __restrict__ R_acc,
                                              const float* __restrict__ raw_alpha) {
  float mid = Sc[i] + cvec[i] + b2[i];
  float rr = R_acc[i] * INV_QQ;
  float lb = mid - rr;
  float ub = mid + rr;
  float alpha = 1.f / (1.f + expf(-raw_alpha[i]));
  float denom = ub - lb;
  float slope = (denom == 0.f) ? 0.f : ub / denom;
  bool below = ub <= 0.f, above = lb >= 0.f;
  bool crossing = !(below || above);
  float base = above ? 1.f : 0.f;
  ReluVals v;
  v.uslope = crossing ? slope : base;
  v.uinter = crossing ? (1.f - slope) * ub : 0.f;
  float l1 = crossing ? 0.f : base;
  float l2 = crossing ? 1.f : base;
  v.lslope = alpha * l1 + (1.f - alpha) * l2;
  return v;
}

__global__ __launch_bounds__(256) void patch_diag(float* __restrict__ out,
                                                  const float* __restrict__ cvec,
                                                  const float* __restrict__ Sc,
                                                  const float* __restrict__ b2,
                                                  const float* __restrict__ R_acc,
                                                  const float* __restrict__ raw_alpha) {
  const size_t NN = (size_t)N * N;
  int i = blockIdx.x * 256 + threadIdx.x;          // 0..N-1
  ReluVals v = relu_vals(i, cvec, Sc, b2, R_acc, raw_alpha);
  out[(size_t)i * (N + 1)] = v.lslope;             // diag(lslope)
  out[NN + N + (size_t)i * (N + 1)] = v.uslope;    // diag(uslope)
  out[2 * NN + N + i] = v.uinter;                  // uintercept row
}

extern "C" void kernel_launch(void* const* d_in, const int* in_sizes, int n_in,
                              void* d_out, int out_size, void* d_ws, size_t ws_size,
                              hipStream_t stream) {
  const float* raw_alpha = (const float*)d_in[0];
  const float* lb0 = (const float*)d_in[1];
  const float* ub0 = (const float*)d_in[2];
  const float* W1 = (const float*)d_in[3];
  const float* b1 = (const float*)d_in[4];
  const float* W2 = (const float*)d_in[5];
  const float* b2 = (const float*)d_in[6];

  float* tvec = (float*)d_ws;        // [N]  W1 @ center         (atomic-accum)
  float* cvec = tvec + N;            // [N]  b1 @ W2^T           (atomic-accum)
  float* Sc = cvec + N;              // [N]  W2 @ tvec           (atomic-accum)
  float* R_acc = Sc + N;             // [N]  eps-weighted row L1 (atomic-accum)

  // d_out (134 MB) doubles as fp8 blocked scratch until the final fill
  unsigned char* W2q = (unsigned char*)d_out;        // [N*N] fp8 blocked, 16 MB
  unsigned char* W1Tq = W2q + (size_t)N * N;         // [N*N] fp8 blocked, 16 MB

  (void)hipMemsetAsync(d_ws, 0, 4 * N * sizeof(float), stream);
  prep_w1<<<dim3(N / 64, N / 64), 256, 0, stream>>>(W1, lb0, ub0, W1Tq, tvec);
  convert_w2<<<dim3(N / 128, N / 128), 256, 0, stream>>>(W2, b1, tvec, W2q, cvec, Sc);
  gemm_absrow<<<dim3(16, 16), 512, 0, stream>>>(W2q, W1Tq, lb0, ub0, R_acc);
  // bulk zero-fill (peak write BW), then sparse diagonal/vector patch
  (void)hipMemsetAsync(d_out, 0, (size_t)out_size * sizeof(float), stream);
  patch_diag<<<N / 256, 256, 0, stream>>>((float*)d_out, cvec, Sc, b2, R_acc, raw_alpha);
}

// Round 6
// 332.314 us; speedup vs baseline: 1.0219x; 1.0219x over previous
//
#include <hip/hip_runtime.h>
#include <stdint.h>

#define N 4096

// blocked scratch layout: addr = tile*524288 + kt*16384 + c*2048 + r*16
//   tile = row>>7, r = row&127, kt = kbyte>>7, c = (kbyte>>4)&7
#define TILE_BYTES 524288   // 128 rows * 4096 B
#define KT_BYTES   16384    // 8 chunks * 128 rows * 16 B

#define QSCALE 256.0f            // W -> fp8 software scale (per tensor)
#define INV_QQ (1.0f / 65536.0f) // undo QSCALE^2 on S

typedef int v8i __attribute__((ext_vector_type(8)));
typedef float f32x16 __attribute__((ext_vector_type(16)));
typedef unsigned int u32x4 __attribute__((ext_vector_type(4)));

union V8 { v8i v; u32x4 h[2]; };

__device__ __forceinline__ void gload16(const unsigned char* g, unsigned char* l) {
  __builtin_amdgcn_global_load_lds(
      (const __attribute__((address_space(1))) unsigned int*)g,
      (__attribute__((address_space(3))) unsigned int*)l, 16, 0, 0);
}

// pack 4 floats -> 4 fp8 e4m3 bytes (OCP on gfx950)
__device__ __forceinline__ int pack4_fp8(float a, float b, float c, float d) {
  int r = __builtin_amdgcn_cvt_pk_fp8_f32(a, b, 0, false);
  r = __builtin_amdgcn_cvt_pk_fp8_f32(c, d, r, true);
  return r;
}

// ---- K1: W1 fp32 [k][j] -> fp8 W1T blocked  +  tvec[k] += W1[k][:] . center ----
__global__ __launch_bounds__(256) void prep_w1(const float* __restrict__ W1,
                                               const float* __restrict__ lb0,
                                               const float* __restrict__ ub0,
                                               unsigned char* __restrict__ W1T,
                                               float* __restrict__ tvec) {
  __shared__ float tile[64 * 65];
  __shared__ float tdot[64];
  const int t = threadIdx.x;
  const int j0 = blockIdx.x * 64, k0 = blockIdx.y * 64;
#pragma unroll
  for (int s = 0; s < 4; ++s) {
    int ck = s * 256 + t;
    int row = ck >> 4;             // k_local 0..63
    int col = (ck & 15) * 4;       // j_local
    float4 v = *(const float4*)(W1 + (size_t)(k0 + row) * N + j0 + col);
    float4 l = *(const float4*)(lb0 + j0 + col);
    float4 u = *(const float4*)(ub0 + j0 + col);
    float part = v.x * 0.5f * (l.x + u.x) + v.y * 0.5f * (l.y + u.y)
               + v.z * 0.5f * (l.z + u.z) + v.w * 0.5f * (l.w + u.w);
    part += __shfl_xor(part, 1, 64);
    part += __shfl_xor(part, 2, 64);
    part += __shfl_xor(part, 4, 64);
    part += __shfl_xor(part, 8, 64);
    if ((t & 15) == 0) tdot[row] = part;   // each row written exactly once
    float* d = &tile[row * 65 + col];
    d[0] = v.x; d[1] = v.y; d[2] = v.z; d[3] = v.w;
  }
  __syncthreads();
  if (t < 64) atomicAdd(&tvec[k0 + t], tdot[t]);
  int jl = t & 63, ch = (t >> 6) * 16;  // coalesced store mapping
  float f[16];
#pragma unroll
  for (int m = 0; m < 16; ++m) f[m] = tile[(ch + m) * 65 + jl] * QSCALE;
  uint4 o;
  o.x = (unsigned)pack4_fp8(f[0], f[1], f[2], f[3]);
  o.y = (unsigned)pack4_fp8(f[4], f[5], f[6], f[7]);
  o.z = (unsigned)pack4_fp8(f[8], f[9], f[10], f[11]);
  o.w = (unsigned)pack4_fp8(f[12], f[13], f[14], f[15]);
  int j = j0 + jl;
  int kb = k0 + ch;                     // k byte index
  *(uint4*)(W1T + (size_t)(j >> 7) * TILE_BYTES + (size_t)(kb >> 7) * KT_BYTES
            + (size_t)((kb >> 4) & 7) * 2048 + (j & 127) * 16) = o;
}

// ---- K2: W2 -> fp8 blocked, coalesced loads along k, shfl-reduced dots ----
__global__ __launch_bounds__(256) void convert_w2(const float* __restrict__ W2,
                                                  const float* __restrict__ b1,
                                                  const float* __restrict__ tvec,
                                                  unsigned char* __restrict__ W2q,
                                                  float* __restrict__ cvec,
                                                  float* __restrict__ Sc) {
  __shared__ int lpack[128][33];          // +1 pad: conflict-free transpose
  const int t = threadIdx.x;
  const int i0 = blockIdx.y * 128;        // row tile
  const int k0 = blockIdx.x * 128;        // k panel
  const int kl = (t & 31) * 4;            // k offset within panel (floats)
  const int rsub = t >> 5;                // 0..7: row sub-index
  float4 bv = *(const float4*)(b1 + k0 + kl);
  float4 tv = *(const float4*)(tvec + k0 + kl);
#pragma unroll
  for (int s = 0; s < 16; ++s) {
    int row = s * 8 + rsub;
    float4 w = *(const float4*)(W2 + (size_t)(i0 + row) * N + k0 + kl);
    float db = w.x * bv.x + w.y * bv.y + w.z * bv.z + w.w * bv.w;
    float dt = w.x * tv.x + w.y * tv.y + w.z * tv.z + w.w * tv.w;
    db += __shfl_xor(db, 1, 64);  dt += __shfl_xor(dt, 1, 64);
    db += __shfl_xor(db, 2, 64);  dt += __shfl_xor(dt, 2, 64);
    db += __shfl_xor(db, 4, 64);  dt += __shfl_xor(dt, 4, 64);
    db += __shfl_xor(db, 8, 64);  dt += __shfl_xor(dt, 8, 64);
    db += __shfl_xor(db, 16, 64); dt += __shfl_xor(dt, 16, 64);
    if ((t & 31) == 0) {
      atomicAdd(&cvec[i0 + row], db);
      atomicAdd(&Sc[i0 + row], dt);
    }
    lpack[row][t & 31] = pack4_fp8(w.x * QSCALE, w.y * QSCALE,
                                   w.z * QSCALE, w.w * QSCALE);
  }
  __syncthreads();
  unsigned char* panel = W2q + (size_t)blockIdx.y * TILE_BYTES
                       + (size_t)blockIdx.x * KT_BYTES;
#pragma unroll
  for (int q = 0; q < 4; ++q) {
    int cid = q * 256 + t;                // 16-B chunk id 0..1023
    int r = cid & 127, c = cid >> 7;
    uint4 o;
    o.x = (unsigned)lpack[r][4 * c + 0];
    o.y = (unsigned)lpack[r][4 * c + 1];
    o.z = (unsigned)lpack[r][4 * c + 2];
    o.w = (unsigned)lpack[r][4 * c + 3];
    *(uint4*)(panel + (size_t)c * 2048 + r * 16) = o;   // consecutive r -> contiguous
  }
}

// ---- K3: R_i = sum_j |(W2q @ W1Tq^T)_ij| * eps_j  via MX fp8 MFMA 32x32x64 ----
// r1 slot/staging/barrier structure, but 1024 threads = 16 waves = 4 waves/SIMD
// (all prior rounds ran 2/SIMD; all pipes <35% => latency-bound, TLP is the
// untested lever). 4x4 wave grid, per-wave 64x64 output, acc[2][2] = 64 VGPR.
#define NT 32   // K tiles of 128 bytes
__global__ __launch_bounds__(1024, 4) void gemm_absrow(const unsigned char* __restrict__ A,  // W2q blocked
                                                       const unsigned char* __restrict__ B,  // W1Tq blocked
                                                       const float* __restrict__ lb0,
                                                       const float* __restrict__ ub0,
                                                       float* __restrict__ R_acc) {
  __shared__ __align__(16) unsigned char sm[4 * 32768];   // 128 KB, 4 k-half groups
  const int t = threadIdx.x;                // 0..1023
  const int lane = t & 63, w = t >> 6;      // 16 waves
  const int wr = w >> 2, wc = w & 3;        // 4 x 4 wave grid
  const int l31 = lane & 31, half = lane >> 5;

  // bijective XCD swizzle (256 blocks, 256 % 8 == 0)
  const int bid = blockIdx.y * 16 + blockIdx.x;
  const int swz = (bid & 7) * 32 + (bid >> 3);
  const int bm = swz >> 4, bn = swz & 15;
  const int i0 = bm * 256, j0 = bn * 256;

  const unsigned char* gA0 = A + (size_t)(2 * bm) * TILE_BYTES;   // rows 0-127
  const unsigned char* gA1 = gA0 + TILE_BYTES;                    // rows 128-255
  const unsigned char* gB0 = B + (size_t)(2 * bn) * TILE_BYTES;
  const unsigned char* gB1 = gB0 + TILE_BYTES;
  const unsigned char* srcA = (w < 8) ? gA0 : gA1;
  const unsigned char* srcB = (w < 8) ? gB0 : gB1;
  const int wo = (w & 7) * 1024 + lane * 16;   // per-lane src offset (== dest offset mod 8192)

  f32x16 acc[2][2] = {};
  const int sc1 = 0x7F7F7F7F;  // E8M0 scale = 1.0 in all 4 bytes

  // stage tile kt, k-half h -> slot ((kt&1)<<1)|h.  2 gload16 per thread:
  // A 16 KB at [0,16K), B 16 KB at [16K,32K); wave w owns 1 KB of each.
  auto stage = [&](int kt, int h) {
    const int g = ((kt & 1) << 1) | h;
    unsigned char* d = sm + g * 32768 + w * 1024 + lane * 16;
    const size_t off = (size_t)kt * KT_BYTES + (size_t)h * 8192;
    gload16(srcA + off + wo, d);
    gload16(srcB + off + wo, d + 16384);
  };

  // in-slot addressing: region(A)= (R>>7)*8192 + c'*2048 + (R&127)*16, c'=half*2+{0,1}
  const int R0 = wr * 64;                 // A row base for this wave (tm adds 32)
  const int J0 = wc * 64;                 // B col base (tn adds 32)
  const unsigned aoff0 = (unsigned)(((R0 >> 7) * 8192) + ((R0 & 127) + l31) * 16 + (half * 2) * 2048);
  const unsigned boff0 = (unsigned)(16384 + ((J0 >> 7) * 8192) + ((J0 & 127) + l31) * 16 + (half * 2) * 2048);

  auto compute = [&](int kt, int h) {
    const unsigned char* base = sm + (((kt & 1) << 1) | h) * 32768;
    V8 af[2], bf[2];
#pragma unroll
    for (int tm = 0; tm < 2; ++tm) {
      const unsigned char* p = base + aoff0 + tm * 512;   // +32 rows
      af[tm].h[0] = *(const u32x4*)p;
      af[tm].h[1] = *(const u32x4*)(p + 2048);            // next 16-B k-chunk
    }
#pragma unroll
    for (int tn = 0; tn < 2; ++tn) {
      const unsigned char* p = base + boff0 + tn * 512;   // +32 cols
      bf[tn].h[0] = *(const u32x4*)p;
      bf[tn].h[1] = *(const u32x4*)(p + 2048);
    }
    __builtin_amdgcn_s_setprio(1);
#pragma unroll
    for (int tm = 0; tm < 2; ++tm)
#pragma unroll
      for (int tn = 0; tn < 2; ++tn)
        acc[tm][tn] = __builtin_amdgcn_mfma_scale_f32_32x32x64_f8f6f4(
            af[tm].v, bf[tn].v, acc[tm][tn],
            0 /*cbsz: fp8*/, 0 /*blgp: fp8*/,
            0, sc1, 0, sc1);
    __builtin_amdgcn_s_setprio(0);
  };

  // prologue: groups (0,0),(0,1) -> 4 loads/wave in flight
  stage(0, 0);
  stage(0, 1);

  for (int kt = 0; kt < NT - 1; ++kt) {
#pragma unroll
    for (int h = 0; h < 2; ++h) {
      stage(kt + 1, h);                                  // now 6 in flight
      asm volatile("s_waitcnt vmcnt(4)" ::: "memory");   // oldest stage landed
      __builtin_amdgcn_s_barrier();                      // ... in all waves
      asm volatile("" ::: "memory");
      compute(kt, h);
    }
  }
  // tail: kt = NT-1, nothing left to stage
  asm volatile("s_waitcnt vmcnt(2)" ::: "memory");
  __builtin_amdgcn_s_barrier();
  asm volatile("" ::: "memory");
  compute(NT - 1, 0);
  asm volatile("s_waitcnt vmcnt(0)" ::: "memory");
  __builtin_amdgcn_s_barrier();
  asm volatile("" ::: "memory");
  compute(NT - 1, 1);

  // epilogue: eps-weighted row L1 norm. C/D 32x32 layout:
  // col = lane&31, row = (r&3) + 8*(r>>2) + 4*(lane>>5)
  float epsv[2];
#pragma unroll
  for (int tn = 0; tn < 2; ++tn) {
    int j = j0 + wc * 64 + tn * 32 + l31;
    epsv[tn] = 0.5f * (ub0[j] - lb0[j]);
  }
#pragma unroll
  for (int tm = 0; tm < 2; ++tm) {
#pragma unroll
    for (int r = 0; r < 16; ++r) {
      float s = fabsf(acc[tm][0][r]) * epsv[0] + fabsf(acc[tm][1][r]) * epsv[1];
#pragma unroll
      for (int off = 1; off < 32; off <<= 1)   // reduce within each 32-lane half
        s += __shfl_xor(s, off, 64);
      if (l31 == 0) {
        int i = i0 + wr * 64 + tm * 32 + (r & 3) + 8 * (r >> 2) + 4 * half;
        atomicAdd(&R_acc[i], s);
      }
    }
  }
}

// ---- K4: sparse DeepPolyReLU patch after bulk hipMemsetAsync zero-fill ----
struct ReluVals { float lslope, uslope, uinter; };

__device__ __forceinline__ ReluVals relu_vals(int i,
                                              const float* __restrict__ cvec,
                                              const float* __restrict__ Sc,
                                              const float* __restrict__ b2,
                                              const float* __restrict__ R_acc,
                                              const float* __restrict__ raw_alpha) {
  float mid = Sc[i] + cvec[i] + b2[i];
  float rr = R_acc[i] * INV_QQ;
  float lb = mid - rr;
  float ub = mid + rr;
  float alpha = 1.f / (1.f + expf(-raw_alpha[i]));
  float denom = ub - lb;
  float slope = (denom == 0.f) ? 0.f : ub / denom;
  bool below = ub <= 0.f, above = lb >= 0.f;
  bool crossing = !(below || above);
  float base = above ? 1.f : 0.f;
  ReluVals v;
  v.uslope = crossing ? slope : base;
  v.uinter = crossing ? (1.f - slope) * ub : 0.f;
  float l1 = crossing ? 0.f : base;
  float l2 = crossing ? 1.f : base;
  v.lslope = alpha * l1 + (1.f - alpha) * l2;
  return v;
}

__global__ __launch_bounds__(256) void patch_diag(float* __restrict__ out,
                                                  const float* __restrict__ cvec,
                                                  const float* __restrict__ Sc,
                                                  const float* __restrict__ b2,
                                                  const float* __restrict__ R_acc,
                                                  const float* __restrict__ raw_alpha) {
  const size_t NN = (size_t)N * N;
  int i = blockIdx.x * 256 + threadIdx.x;          // 0..N-1
  ReluVals v = relu_vals(i, cvec, Sc, b2, R_acc, raw_alpha);
  out[(size_t)i * (N + 1)] = v.lslope;             // diag(lslope)
  out[NN + N + (size_t)i * (N + 1)] = v.uslope;    // diag(uslope)
  out[2 * NN + N + i] = v.uinter;                  // uintercept row
}

extern "C" void kernel_launch(void* const* d_in, const int* in_sizes, int n_in,
                              void* d_out, int out_size, void* d_ws, size_t ws_size,
                              hipStream_t stream) {
  const float* raw_alpha = (const float*)d_in[0];
  const float* lb0 = (const float*)d_in[1];
  const float* ub0 = (const float*)d_in[2];
  const float* W1 = (const float*)d_in[3];
  const float* b1 = (const float*)d_in[4];
  const float* W2 = (const float*)d_in[5];
  const float* b2 = (const float*)d_in[6];

  float* tvec = (float*)d_ws;        // [N]  W1 @ center         (atomic-accum)
  float* cvec = tvec + N;            // [N]  b1 @ W2^T           (atomic-accum)
  float* Sc = cvec + N;              // [N]  W2 @ tvec           (atomic-accum)
  float* R_acc = Sc + N;             // [N]  eps-weighted row L1 (atomic-accum)

  // d_out (134 MB) doubles as fp8 blocked scratch until the final fill
  unsigned char* W2q = (unsigned char*)d_out;        // [N*N] fp8 blocked, 16 MB
  unsigned char* W1Tq = W2q + (size_t)N * N;         // [N*N] fp8 blocked, 16 MB

  (void)hipMemsetAsync(d_ws, 0, 4 * N * sizeof(float), stream);
  prep_w1<<<dim3(N / 64, N / 64), 256, 0, stream>>>(W1, lb0, ub0, W1Tq, tvec);
  convert_w2<<<dim3(N / 128, N / 128), 256, 0, stream>>>(W2, b1, tvec, W2q, cvec, Sc);
  gemm_absrow<<<dim3(16, 16), 1024, 0, stream>>>(W2q, W1Tq, lb0, ub0, R_acc);
  // bulk zero-fill (peak write BW), then sparse diagonal/vector patch
  (void)hipMemsetAsync(d_out, 0, (size_t)out_size * sizeof(float), stream);
  patch_diag<<<N / 256, 256, 0, stream>>>((float*)d_out, cvec, Sc, b2, R_acc, raw_alpha);
}

// Round 7
// 318.363 us; speedup vs baseline: 1.0667x; 1.0438x over previous
//
#include <hip/hip_runtime.h>
#include <stdint.h>

#define N 4096

// blocked scratch layout: addr = tile*524288 + kt*16384 + c*2048 + r*16
//   tile = row>>7, r = row&127, kt = kbyte>>7, c = (kbyte>>4)&7
#define TILE_BYTES 524288   // 128 rows * 4096 B
#define KT_BYTES   16384    // 8 chunks * 128 rows * 16 B

#define QSCALE 256.0f            // W -> fp8 software scale (per tensor)
#define INV_QQ (1.0f / 65536.0f) // undo QSCALE^2 on S

typedef int v8i __attribute__((ext_vector_type(8)));
typedef float f32x16 __attribute__((ext_vector_type(16)));
typedef unsigned int u32x4 __attribute__((ext_vector_type(4)));

union V8 { v8i v; u32x4 h[2]; };

__device__ __forceinline__ void gload16(const unsigned char* g, unsigned char* l) {
  __builtin_amdgcn_global_load_lds(
      (const __attribute__((address_space(1))) unsigned int*)g,
      (__attribute__((address_space(3))) unsigned int*)l, 16, 0, 0);
}

// pack 4 floats -> 4 fp8 e4m3 bytes (OCP on gfx950)
__device__ __forceinline__ int pack4_fp8(float a, float b, float c, float d) {
  int r = __builtin_amdgcn_cvt_pk_fp8_f32(a, b, 0, false);
  r = __builtin_amdgcn_cvt_pk_fp8_f32(c, d, r, true);
  return r;
}

// ---- K1: W1 fp32 [k][j] -> fp8 W1T blocked  +  tvec[k] += W1[k][:] . center ----
__global__ __launch_bounds__(256) void prep_w1(const float* __restrict__ W1,
                                               const float* __restrict__ lb0,
                                               const float* __restrict__ ub0,
                                               unsigned char* __restrict__ W1T,
                                               float* __restrict__ tvec) {
  __shared__ float tile[64 * 65];
  __shared__ float tdot[64];
  const int t = threadIdx.x;
  const int j0 = blockIdx.x * 64, k0 = blockIdx.y * 64;
#pragma unroll
  for (int s = 0; s < 4; ++s) {
    int ck = s * 256 + t;
    int row = ck >> 4;             // k_local 0..63
    int col = (ck & 15) * 4;       // j_local
    float4 v = *(const float4*)(W1 + (size_t)(k0 + row) * N + j0 + col);
    float4 l = *(const float4*)(lb0 + j0 + col);
    float4 u = *(const float4*)(ub0 + j0 + col);
    float part = v.x * 0.5f * (l.x + u.x) + v.y * 0.5f * (l.y + u.y)
               + v.z * 0.5f * (l.z + u.z) + v.w * 0.5f * (l.w + u.w);
    part += __shfl_xor(part, 1, 64);
    part += __shfl_xor(part, 2, 64);
    part += __shfl_xor(part, 4, 64);
    part += __shfl_xor(part, 8, 64);
    if ((t & 15) == 0) tdot[row] = part;   // each row written exactly once
    float* d = &tile[row * 65 + col];
    d[0] = v.x; d[1] = v.y; d[2] = v.z; d[3] = v.w;
  }
  __syncthreads();
  if (t < 64) atomicAdd(&tvec[k0 + t], tdot[t]);
  int jl = t & 63, ch = (t >> 6) * 16;  // coalesced store mapping
  float f[16];
#pragma unroll
  for (int m = 0; m < 16; ++m) f[m] = tile[(ch + m) * 65 + jl] * QSCALE;
  uint4 o;
  o.x = (unsigned)pack4_fp8(f[0], f[1], f[2], f[3]);
  o.y = (unsigned)pack4_fp8(f[4], f[5], f[6], f[7]);
  o.z = (unsigned)pack4_fp8(f[8], f[9], f[10], f[11]);
  o.w = (unsigned)pack4_fp8(f[12], f[13], f[14], f[15]);
  int j = j0 + jl;
  int kb = k0 + ch;                     // k byte index
  *(uint4*)(W1T + (size_t)(j >> 7) * TILE_BYTES + (size_t)(kb >> 7) * KT_BYTES
            + (size_t)((kb >> 4) & 7) * 2048 + (j & 127) * 16) = o;
}

// ---- K2: W2 -> fp8 blocked, coalesced loads along k, shfl-reduced dots ----
__global__ __launch_bounds__(256) void convert_w2(const float* __restrict__ W2,
                                                  const float* __restrict__ b1,
                                                  const float* __restrict__ tvec,
                                                  unsigned char* __restrict__ W2q,
                                                  float* __restrict__ cvec,
                                                  float* __restrict__ Sc) {
  __shared__ int lpack[128][33];          // +1 pad: conflict-free transpose
  const int t = threadIdx.x;
  const int i0 = blockIdx.y * 128;        // row tile
  const int k0 = blockIdx.x * 128;        // k panel
  const int kl = (t & 31) * 4;            // k offset within panel (floats)
  const int rsub = t >> 5;                // 0..7: row sub-index
  float4 bv = *(const float4*)(b1 + k0 + kl);
  float4 tv = *(const float4*)(tvec + k0 + kl);
#pragma unroll
  for (int s = 0; s < 16; ++s) {
    int row = s * 8 + rsub;
    float4 w = *(const float4*)(W2 + (size_t)(i0 + row) * N + k0 + kl);
    float db = w.x * bv.x + w.y * bv.y + w.z * bv.z + w.w * bv.w;
    float dt = w.x * tv.x + w.y * tv.y + w.z * tv.z + w.w * tv.w;
    db += __shfl_xor(db, 1, 64);  dt += __shfl_xor(dt, 1, 64);
    db += __shfl_xor(db, 2, 64);  dt += __shfl_xor(dt, 2, 64);
    db += __shfl_xor(db, 4, 64);  dt += __shfl_xor(dt, 4, 64);
    db += __shfl_xor(db, 8, 64);  dt += __shfl_xor(dt, 8, 64);
    db += __shfl_xor(db, 16, 64); dt += __shfl_xor(dt, 16, 64);
    if ((t & 31) == 0) {
      atomicAdd(&cvec[i0 + row], db);
      atomicAdd(&Sc[i0 + row], dt);
    }
    lpack[row][t & 31] = pack4_fp8(w.x * QSCALE, w.y * QSCALE,
                                   w.z * QSCALE, w.w * QSCALE);
  }
  __syncthreads();
  unsigned char* panel = W2q + (size_t)blockIdx.y * TILE_BYTES
                       + (size_t)blockIdx.x * KT_BYTES;
#pragma unroll
  for (int q = 0; q < 4; ++q) {
    int cid = q * 256 + t;                // 16-B chunk id 0..1023
    int r = cid & 127, c = cid >> 7;
    uint4 o;
    o.x = (unsigned)lpack[r][4 * c + 0];
    o.y = (unsigned)lpack[r][4 * c + 1];
    o.z = (unsigned)lpack[r][4 * c + 2];
    o.w = (unsigned)lpack[r][4 * c + 3];
    *(uint4*)(panel + (size_t)c * 2048 + r * 16) = o;   // consecutive r -> contiguous
  }
}

// ---- K3: R_i = sum_j |(W2q @ W1Tq^T)_ij| * eps_j  via MX fp8 MFMA 32x32x64 ----
// r6 version: 1024 threads = 16 waves = 4 waves/SIMD, 4x4 wave grid,
// per-wave 64x64 output, acc[2][2]. Kept as-is (best measured 84.4 us).
#define NT 32   // K tiles of 128 bytes
__global__ __launch_bounds__(1024, 4) void gemm_absrow(const unsigned char* __restrict__ A,  // W2q blocked
                                                       const unsigned char* __restrict__ B,  // W1Tq blocked
                                                       const float* __restrict__ lb0,
                                                       const float* __restrict__ ub0,
                                                       float* __restrict__ R_acc) {
  __shared__ __align__(16) unsigned char sm[4 * 32768];   // 128 KB, 4 k-half groups
  const int t = threadIdx.x;                // 0..1023
  const int lane = t & 63, w = t >> 6;      // 16 waves
  const int wr = w >> 2, wc = w & 3;        // 4 x 4 wave grid
  const int l31 = lane & 31, half = lane >> 5;

  // bijective XCD swizzle (256 blocks, 256 % 8 == 0)
  const int bid = blockIdx.y * 16 + blockIdx.x;
  const int swz = (bid & 7) * 32 + (bid >> 3);
  const int bm = swz >> 4, bn = swz & 15;
  const int i0 = bm * 256, j0 = bn * 256;

  const unsigned char* gA0 = A + (size_t)(2 * bm) * TILE_BYTES;   // rows 0-127
  const unsigned char* gA1 = gA0 + TILE_BYTES;                    // rows 128-255
  const unsigned char* gB0 = B + (size_t)(2 * bn) * TILE_BYTES;
  const unsigned char* gB1 = gB0 + TILE_BYTES;
  const unsigned char* srcA = (w < 8) ? gA0 : gA1;
  const unsigned char* srcB = (w < 8) ? gB0 : gB1;
  const int wo = (w & 7) * 1024 + lane * 16;   // per-lane src offset (== dest offset mod 8192)

  f32x16 acc[2][2] = {};
  const int sc1 = 0x7F7F7F7F;  // E8M0 scale = 1.0 in all 4 bytes

  // stage tile kt, k-half h -> slot ((kt&1)<<1)|h.  2 gload16 per thread:
  // A 16 KB at [0,16K), B 16 KB at [16K,32K); wave w owns 1 KB of each.
  auto stage = [&](int kt, int h) {
    const int g = ((kt & 1) << 1) | h;
    unsigned char* d = sm + g * 32768 + w * 1024 + lane * 16;
    const size_t off = (size_t)kt * KT_BYTES + (size_t)h * 8192;
    gload16(srcA + off + wo, d);
    gload16(srcB + off + wo, d + 16384);
  };

  // in-slot addressing: region(A)= (R>>7)*8192 + c'*2048 + (R&127)*16, c'=half*2+{0,1}
  const int R0 = wr * 64;                 // A row base for this wave (tm adds 32)
  const int J0 = wc * 64;                 // B col base (tn adds 32)
  const unsigned aoff0 = (unsigned)(((R0 >> 7) * 8192) + ((R0 & 127) + l31) * 16 + (half * 2) * 2048);
  const unsigned boff0 = (unsigned)(16384 + ((J0 >> 7) * 8192) + ((J0 & 127) + l31) * 16 + (half * 2) * 2048);

  auto compute = [&](int kt, int h) {
    const unsigned char* base = sm + (((kt & 1) << 1) | h) * 32768;
    V8 af[2], bf[2];
#pragma unroll
    for (int tm = 0; tm < 2; ++tm) {
      const unsigned char* p = base + aoff0 + tm * 512;   // +32 rows
      af[tm].h[0] = *(const u32x4*)p;
      af[tm].h[1] = *(const u32x4*)(p + 2048);            // next 16-B k-chunk
    }
#pragma unroll
    for (int tn = 0; tn < 2; ++tn) {
      const unsigned char* p = base + boff0 + tn * 512;   // +32 cols
      bf[tn].h[0] = *(const u32x4*)p;
      bf[tn].h[1] = *(const u32x4*)(p + 2048);
    }
    __builtin_amdgcn_s_setprio(1);
#pragma unroll
    for (int tm = 0; tm < 2; ++tm)
#pragma unroll
      for (int tn = 0; tn < 2; ++tn)
        acc[tm][tn] = __builtin_amdgcn_mfma_scale_f32_32x32x64_f8f6f4(
            af[tm].v, bf[tn].v, acc[tm][tn],
            0 /*cbsz: fp8*/, 0 /*blgp: fp8*/,
            0, sc1, 0, sc1);
    __builtin_amdgcn_s_setprio(0);
  };

  // prologue: groups (0,0),(0,1) -> 4 loads/wave in flight
  stage(0, 0);
  stage(0, 1);

  for (int kt = 0; kt < NT - 1; ++kt) {
#pragma unroll
    for (int h = 0; h < 2; ++h) {
      stage(kt + 1, h);                                  // now 6 in flight
      asm volatile("s_waitcnt vmcnt(4)" ::: "memory");   // oldest stage landed
      __builtin_amdgcn_s_barrier();                      // ... in all waves
      asm volatile("" ::: "memory");
      compute(kt, h);
    }
  }
  // tail: kt = NT-1, nothing left to stage
  asm volatile("s_waitcnt vmcnt(2)" ::: "memory");
  __builtin_amdgcn_s_barrier();
  asm volatile("" ::: "memory");
  compute(NT - 1, 0);
  asm volatile("s_waitcnt vmcnt(0)" ::: "memory");
  __builtin_amdgcn_s_barrier();
  asm volatile("" ::: "memory");
  compute(NT - 1, 1);

  // epilogue: eps-weighted row L1 norm. C/D 32x32 layout:
  // col = lane&31, row = (r&3) + 8*(r>>2) + 4*(lane>>5)
  float epsv[2];
#pragma unroll
  for (int tn = 0; tn < 2; ++tn) {
    int j = j0 + wc * 64 + tn * 32 + l31;
    epsv[tn] = 0.5f * (ub0[j] - lb0[j]);
  }
#pragma unroll
  for (int tm = 0; tm < 2; ++tm) {
#pragma unroll
    for (int r = 0; r < 16; ++r) {
      float s = fabsf(acc[tm][0][r]) * epsv[0] + fabsf(acc[tm][1][r]) * epsv[1];
#pragma unroll
      for (int off = 1; off < 32; off <<= 1)   // reduce within each 32-lane half
        s += __shfl_xor(s, off, 64);
      if (l31 == 0) {
        int i = i0 + wr * 64 + tm * 32 + (r & 3) + 8 * (r >> 2) + 4 * half;
        atomicAdd(&R_acc[i], s);
      }
    }
  }
}

// ---- K4: sparse DeepPolyReLU patch after bulk hipMemsetAsync zero-fill ----
struct ReluVals { float lslope, uslope, uinter; };

__device__ __forceinline__ ReluVals relu_vals(int i,
                                              const float* __restrict__ cvec,
                                              const float* __restrict__ Sc,
                                              const float* __restrict__ b2,
                                              const float* __restrict__ R_acc,
                                              const float* __restrict__ raw_alpha) {
  float mid = Sc[i] + cvec[i] + b2[i];
  float rr = R_acc[i] * INV_QQ;
  float lb = mid - rr;
  float ub = mid + rr;
  float alpha = 1.f / (1.f + expf(-raw_alpha[i]));
  float denom = ub - lb;
  float slope = (denom == 0.f) ? 0.f : ub / denom;
  bool below = ub <= 0.f, above = lb >= 0.f;
  bool crossing = !(below || above);
  float base = above ? 1.f : 0.f;
  ReluVals v;
  v.uslope = crossing ? slope : base;
  v.uinter = crossing ? (1.f - slope) * ub : 0.f;
  float l1 = crossing ? 0.f : base;
  float l2 = crossing ? 1.f : base;
  v.lslope = alpha * l1 + (1.f - alpha) * l2;
  return v;
}

__global__ __launch_bounds__(256) void patch_diag(float* __restrict__ out,
                                                  const float* __restrict__ cvec,
                                                  const float* __restrict__ Sc,
                                                  const float* __restrict__ b2,
                                                  const float* __restrict__ R_acc,
                                                  const float* __restrict__ raw_alpha) {
  const size_t NN = (size_t)N * N;
  int i = blockIdx.x * 256 + threadIdx.x;          // 0..N-1
  ReluVals v = relu_vals(i, cvec, Sc, b2, R_acc, raw_alpha);
  out[(size_t)i * (N + 1)] = v.lslope;             // diag(lslope)
  out[NN + N + (size_t)i * (N + 1)] = v.uslope;    // diag(uslope)
  out[2 * NN + N + i] = v.uinter;                  // uintercept row
}

extern "C" void kernel_launch(void* const* d_in, const int* in_sizes, int n_in,
                              void* d_out, int out_size, void* d_ws, size_t ws_size,
                              hipStream_t stream) {
  const float* raw_alpha = (const float*)d_in[0];
  const float* lb0 = (const float*)d_in[1];
  const float* ub0 = (const float*)d_in[2];
  const float* W1 = (const float*)d_in[3];
  const float* b1 = (const float*)d_in[4];
  const float* W2 = (const float*)d_in[5];
  const float* b2 = (const float*)d_in[6];

  float* tvec = (float*)d_ws;        // [N]  W1 @ center         (atomic-accum)
  float* cvec = tvec + N;            // [N]  b1 @ W2^T           (atomic-accum)
  float* Sc = cvec + N;              // [N]  W2 @ tvec           (atomic-accum)
  float* R_acc = Sc + N;             // [N]  eps-weighted row L1 (atomic-accum)

  // d_out (134 MB) doubles as fp8 blocked scratch until the final fill
  unsigned char* W2q = (unsigned char*)d_out;        // [N*N] fp8 blocked, 16 MB
  unsigned char* W1Tq = W2q + (size_t)N * N;         // [N*N] fp8 blocked, 16 MB

  (void)hipMemsetAsync(d_ws, 0, 4 * N * sizeof(float), stream);
  prep_w1<<<dim3(N / 64, N / 64), 256, 0, stream>>>(W1, lb0, ub0, W1Tq, tvec);
  convert_w2<<<dim3(N / 128, N / 128), 256, 0, stream>>>(W2, b1, tvec, W2q, cvec, Sc);
  gemm_absrow<<<dim3(16, 16), 1024, 0, stream>>>(W2q, W1Tq, lb0, ub0, R_acc);
  // bulk zero-fill: out_size is in BYTES (r6 counter evidence: memset of
  // out_size*4 showed WRITE_SIZE = 537 MB = 4x the 134.25 MB output)
  (void)hipMemsetAsync(d_out, 0, (size_t)out_size, stream);
  patch_diag<<<N / 256, 256, 0, stream>>>((float*)d_out, cvec, Sc, b2, R_acc, raw_alpha);
}